// Round 12
// baseline (196.384 us; speedup 1.0000x reference)
//
#include <hip/hip_runtime.h>
#include <hip/hip_fp16.h>

typedef int      v4i __attribute__((ext_vector_type(4)));
typedef int      v2i __attribute__((ext_vector_type(2)));
typedef float    v4f __attribute__((ext_vector_type(4)));
typedef _Float16 v8h __attribute__((ext_vector_type(8)));
typedef _Float16 v4h __attribute__((ext_vector_type(4)));

#define MDIM 8192
#define NDIM 4096
#define KDIM 4096
#define RDIM 64
#define KW   (KDIM / 2)
#define NT   (KDIM / 128)        // 32 K-tiles of BK=128 int8 (A staging units)

typedef const __attribute__((address_space(1))) char* gas_ptr;
typedef __attribute__((address_space(3))) char*       las_ptr;

__device__ __forceinline__ void unpack_w(v4i w, int& lo8, int& hi8) {
    unsigned p01 = __builtin_amdgcn_perm((unsigned)w.y, (unsigned)w.x, 0x0C0C0400u);
    unsigned p23 = __builtin_amdgcn_perm((unsigned)w.w, (unsigned)w.z, 0x0C0C0400u);
    unsigned b4  = __builtin_amdgcn_perm(p23, p01, 0x05040100u);
    unsigned lo = b4 & 0x0F0F0F0Fu;
    unsigned hi = (b4 >> 4) & 0x0F0F0F0Fu;
    lo8 = (int)(((lo ^ 0x08080808u) + 0x78787878u) ^ 0x80808080u);
    hi8 = (int)(((hi ^ 0x08080808u) + 0x78787878u) ^ 0x80808080u);
}

// ---- kernel 1: repack. x -> linear int8 rows. w -> lane-major MFMA tiles:
// [n/16 tile][k64 block][lane 0..63][16B], lane l holds col (l&15),
// k = k64*64 + (l>>4)*16 .. +16 -> a B fragment load is 1KB contiguous/wave.
__global__ __launch_bounds__(256)
void repack_int4(const int* __restrict__ xq, const int* __restrict__ wq,
                 char* __restrict__ x8, char* __restrict__ w8t)
{
    const size_t XCH = (size_t)MDIM * KW / 4;
    const size_t TCH = XCH + (size_t)NDIM * KW / 4;
    size_t stride = (size_t)gridDim.x * blockDim.x;
    for (size_t i = (size_t)blockIdx.x * blockDim.x + threadIdx.x; i < TCH; i += stride) {
        v4i w;
        char* dst;
        if (i < XCH) {
            w = *(const v4i*)(xq + i * 4);
            dst = x8 + i * 8;
        } else {
            size_t j = i - XCH;
            w = *(const v4i*)(wq + j * 4);
            int n  = (int)(j >> 9);      // 512 chunks (8 int4 each) per row
            int kc = (int)(j & 511);
            size_t block = (size_t)(n >> 4) * 64 + (kc >> 3);
            int lane = ((kc >> 1) & 3) * 16 + (n & 15);
            dst = w8t + block * 1024 + lane * 16 + (kc & 1) * 8;
        }
        int lo8, hi8;
        unpack_w(w, lo8, hi8);
        *(v2i*)dst = (v2i){lo8, hi8};
    }
}

// ---- kernel 2: 256x256 int8 GEMM, A via LDS, B via L2->registers ----------
// r5 skeleton (merged 4-phase, A [2][2] rotation, 1 barrier/phase) with B
// off the LDS port: LDS traffic/phase 128KB -> 80KB (< MFMA leg), LDS 67KB
// -> 2 blocks/CU (16 waves) for cross-block overlap.
__device__ __forceinline__ void stage2A(const char* g, char* l, int kt, int ks) {
    const char* s = g + kt * 128 + ks * 64;
    __builtin_amdgcn_global_load_lds((gas_ptr)(const void*)s,
                                     (las_ptr)(void*)l, 16, 0, 0);
    __builtin_amdgcn_global_load_lds((gas_ptr)(const void*)(s + (size_t)128 * KDIM),
                                     (las_ptr)(void*)(l + 8192), 16, 0, 0);
}

#define BAR asm volatile("s_barrier" ::: "memory")
#define VM6 asm volatile("s_waitcnt vmcnt(6)" ::: "memory")
#define SGB(m, n) __builtin_amdgcn_sched_group_barrier(m, n, 0)

// weave: 6 VMEM (4 B-loads + 2 A-DMA) early, 8 DS_READ laced, rest MFMA
#define SGBSEQ do {                                                            \
    SGB(0x30, 2); SGB(0x8, 2); SGB(0x30, 2); SGB(0x8, 2);                      \
    SGB(0x30, 2); SGB(0x8, 2);                                                 \
    SGB(0x100, 2); SGB(0x8, 4); SGB(0x100, 2); SGB(0x8, 4);                    \
    SGB(0x100, 2); SGB(0x8, 4); SGB(0x100, 2); SGB(0x8, 4);                    \
    SGB(0x8, 10);                                                              \
} while (0)

#define READ_A8(dst, PAR, KS)                                                  \
    _Pragma("unroll")                                                          \
    for (int ii = 0; ii < 8; ++ii)                                             \
        dst[ii] = *(const v4i*)((const char*)Asub[PAR][KS] + aoff + ii * 1024)

#define LOADB4(dst, K64)                                                       \
    _Pragma("unroll")                                                          \
    for (int jj = 0; jj < 4; ++jj)                                             \
        dst[jj] = *(const v4i*)(gBb + (size_t)jj * 65536 + (size_t)(K64) * 1024)

#define MMA32(AS, BS)                                                          \
    _Pragma("unroll")                                                          \
    for (int ii = 0; ii < 8; ++ii)                                             \
        _Pragma("unroll")                                                      \
        for (int jj = 0; jj < 4; ++jj)                                         \
            acc[ii][jj] = __builtin_amdgcn_mfma_i32_16x16x64_i8(               \
                AS[ii], BS[jj], acc[ii][jj], 0, 0, 0)

// FIFO ledger (per wave; order B4 then A2): entering phase P the queue is
// [B(P)4][A(P-1)2]. Compiler auto-waits the B registers before MMA; manual
// VM6 at phase end leaves [B(P+1)4][A(P)2] -> A(P-1) drained before its
// ds_read at phase P+1. Verified through prologue and steady state.
#define QPHASE(CA, CB, NA, NB, NPAR, NKS, SPAR, SKS, SKT, KB) do {             \
    LOADB4(NB, KB);                                                            \
    stage2A(gA, &Asub[SPAR][SKS][ldsW], SKT, SKS);                             \
    READ_A8(NA, NPAR, NKS);                                                    \
    MMA32(CA, CB);                                                             \
    SGBSEQ;                                                                    \
    VM6; BAR;                                                                  \
} while (0)

__global__ __launch_bounds__(512, 2)
void w4a4_bl2(const char* __restrict__ x8, const char* __restrict__ w8t,
              const float* __restrict__ xsc, const float* __restrict__ wsc,
              const float* __restrict__ bias, const float* __restrict__ xr,
              const float* __restrict__ wo, float* __restrict__ out)
{
    // A only: [parity][k-half][256 rows x 64B], swizzled: byte c of row r
    // holds global col c ^ (((r>>1)&3)<<4). 64 KiB + 3 KiB -> 2 blocks/CU.
    __shared__ __align__(16) char Asub[2][2][16384];
    __shared__ float xs_s[256];
    __shared__ float ws_s[256];
    __shared__ float bs_s[256];

    const int tid  = threadIdx.x;
    const int lane = tid & 63;
    const int wid  = tid >> 6;     // 0..7
    const int wm   = wid >> 2;     // M half (0..1)
    const int wn   = wid & 3;      // N quarter (0..3)

    // XCD-grouped bijective swizzle: each XCD owns 2 B column-panels (2MB,
    // L2-resident) and sweeps 32 M-panels within each.
    const int xcd = blockIdx.x & 7;
    const int seq = blockIdx.x >> 3;          // 0..63
    const int bxn = xcd * 2 + (seq >> 5);     // 0..15
    const int by  = seq & 31;                 // 0..31

    if (tid < 256) {
        xs_s[tid] = xsc[by * 256 + tid];
    } else {
        int n = tid - 256;
        ws_s[n] = wsc[bxn * 256 + n];
        bs_s[n] = bias[bxn * 256 + n];
    }

    // A staging: lane covers 16B of row (wid*16 + lane/4), pre-swizzled col
    const int srow = wid * 16 + (lane >> 2);
    const int scol = ((lane & 3) * 16) ^ (((lane >> 3) & 3) << 4);
    const char* gA = x8 + (size_t)(by * 256 + srow) * KDIM + scol;
    const int ldsW = wid * 1024;

    // B: lane-major tiled layout; wave's 4 n-tiles start at t0
    const char* gBb = w8t + (size_t)(bxn * 16 + wn * 4) * 65536 + lane * 16;

    // A fragment read geometry (16x16x64; swizzle XOR lane-constant)
    const int lr   = lane & 15;
    const int cef  = ((lane >> 4) << 4) ^ (((lr >> 1) & 3) << 4);
    const int aoff = (wm * 128 + lr) * 64 + cef;

    v4i acc[8][4];
#pragma unroll
    for (int i = 0; i < 8; ++i)
#pragma unroll
        for (int j = 0; j < 4; ++j) acc[i][j] = (v4i){0, 0, 0, 0};

    v4i a0[8], a1[8], b0[4], b1[4];

    // prologue: A stages (6 events) then B0 (4); vmcnt(6) drains A00,A01
    // leaving [A10·2? -> no: leaves B0·4 + A10·2] == steady-state pattern.
    stage2A(gA, &Asub[0][0][ldsW], 0, 0);
    stage2A(gA, &Asub[0][1][ldsW], 0, 1);
    LOADB4(b0, 0);
    stage2A(gA, &Asub[1][0][ldsW], 1, 0);
    VM6; BAR;
    READ_A8(a0, 0, 0);

    // A rotation identical to r5 (staged Qi, read Qi+3). B k64 index per
    // phase = the k-window of the NEXT phase's compute; tail clamps to 63
    // (dead loads, uniform counts).
    for (int it = 0; it < NT / 2; ++it) {
        const int kt1 = 2 * it + 1;
        const int kt2 = (2 * it + 2 < NT) ? 2 * it + 2 : NT - 1;
        const int kt3 = (2 * it + 3 < NT) ? 2 * it + 3 : NT - 1;
        const int kb4 = (4 * it + 4 < 64) ? 4 * it + 4 : 63;
        // Q1: compute [0][0] (k64=4it, B=b0); next frags from [0][1]
        QPHASE(a0, b0, a1, b1, 0, 1, 1, 1, kt1, 4 * it + 1);
        // Q2: compute [0][1]; next from [1][0]
        QPHASE(a1, b1, a0, b0, 1, 0, 0, 0, kt2, 4 * it + 2);
        // Q3: compute [1][0]; next from [1][1]
        QPHASE(a0, b0, a1, b1, 1, 1, 0, 1, kt2, 4 * it + 3);
        // Q4: compute [1][1]; next from [0][0] (restaged @kt2)
        QPHASE(a1, b1, a0, b0, 0, 0, 1, 0, kt3, kb4);
    }

    // drain DMAs before overwriting LDS with the f16 outlier tiles
    asm volatile("s_waitcnt vmcnt(0)" ::: "memory");
    BAR;

    // ---- rank-64 outlier staging: f16 [256][64] (128B rows), XOR-swizzled
    // byte ^= ((row&7)<<4). Xh = Asub bytes 0..32K, Wh = 32K..64K.
    char* Xh = (char*)&Asub[0][0][0];
    char* Wh = Xh + 32768;
    {
        const int rr = tid >> 3;          // 0..63
        const int cb = (tid & 7) * 16;    // byte col within 128B row
#pragma unroll
        for (int p = 0; p < 4; ++p) {
            const int row = p * 64 + rr;
            const int sw = cb ^ ((row & 7) << 4);
            v4f x0 = *(const v4f*)(xr + (size_t)(by * 256 + row) * RDIM + (cb >> 1));
            v4f x1 = *(const v4f*)(xr + (size_t)(by * 256 + row) * RDIM + (cb >> 1) + 4);
            v8h hx = {(_Float16)x0[0], (_Float16)x0[1], (_Float16)x0[2], (_Float16)x0[3],
                      (_Float16)x1[0], (_Float16)x1[1], (_Float16)x1[2], (_Float16)x1[3]};
            *(v8h*)(Xh + (size_t)row * 128 + sw) = hx;
            v4f w0 = *(const v4f*)(wo + (size_t)(bxn * 256 + row) * RDIM + (cb >> 1));
            v4f w1 = *(const v4f*)(wo + (size_t)(bxn * 256 + row) * RDIM + (cb >> 1) + 4);
            v8h hw = {(_Float16)w0[0], (_Float16)w0[1], (_Float16)w0[2], (_Float16)w0[3],
                      (_Float16)w1[0], (_Float16)w1[1], (_Float16)w1[2], (_Float16)w1[3]};
            *(v8h*)(Wh + (size_t)row * 128 + sw) = hw;
        }
    }

    // dequant in place (int acc -> f32 bits), overlaps the LDS staging above
#pragma unroll
    for (int i = 0; i < 8; ++i) {
        const int r0 = wm * 128 + i * 16 + ((lane >> 4) << 2);
        const v4f xs4 = *(const v4f*)&xs_s[r0];
#pragma unroll
        for (int j = 0; j < 4; ++j) {
            const int col = wn * 64 + j * 16 + lr;
            const float sw = ws_s[col];
            const float bz = bs_s[col];
            v4f f;
#pragma unroll
            for (int r = 0; r < 4; ++r)
                f[r] = (float)acc[i][j][r] * xs4[r] * sw + bz;
            acc[i][j] = __builtin_bit_cast(v4i, f);
        }
    }
    __syncthreads();

    // rank-64 outlier, f16 MFMA accumulating into the dequantized f32 frags
#pragma unroll
    for (int ks = 0; ks < 2; ++ks) {
        v8h ah[8], bh[4];
#pragma unroll
        for (int i = 0; i < 8; ++i) {
            const int row = wm * 128 + i * 16 + lr;
            const int c   = (ks * 64 + ((lane >> 4) << 4)) ^ ((row & 7) << 4);
            ah[i] = *(const v8h*)(Xh + (size_t)row * 128 + c);
        }
#pragma unroll
        for (int j = 0; j < 4; ++j) {
            const int row = wn * 64 + j * 16 + lr;
            const int c   = (ks * 64 + ((lane >> 4) << 4)) ^ ((row & 7) << 4);
            bh[j] = *(const v8h*)(Wh + (size_t)row * 128 + c);
        }
#pragma unroll
        for (int i = 0; i < 8; ++i)
#pragma unroll
            for (int j = 0; j < 4; ++j) {
                v4f c = __builtin_bit_cast(v4f, acc[i][j]);
                c = __builtin_amdgcn_mfma_f32_16x16x32_f16(ah[i], bh[j], c, 0, 0, 0);
                acc[i][j] = __builtin_bit_cast(v4i, c);
            }
    }

    const size_t obase = (size_t)(by * 256 + wm * 128 + ((lane >> 4) << 2)) * NDIM
                       + bxn * 256 + wn * 64 + lr;
#pragma unroll
    for (int i = 0; i < 8; ++i)
#pragma unroll
        for (int j = 0; j < 4; ++j) {
            v4f f = __builtin_bit_cast(v4f, acc[i][j]);
#pragma unroll
            for (int r = 0; r < 4; ++r)
                out[obase + (size_t)(i * 16 + r) * NDIM + j * 16] = f[r];
        }
}

// ---------------- fallback: fused single-kernel path (ws too small) --------
__global__ __launch_bounds__(256, 2)
void w4a4_fused(const int* __restrict__ xq, const float* __restrict__ xsc,
                const int* __restrict__ wq, const float* __restrict__ wsc,
                const float* __restrict__ bias, const float* __restrict__ xr,
                const float* __restrict__ wo, float* __restrict__ out)
{
    __shared__ __align__(16) char As[128 * 144];
    __shared__ __align__(16) char Bs[128 * 144];
    __shared__ float xs_s[128];
    __shared__ float ws_s[128];
    __shared__ float bs_s[128];

    const int tid  = threadIdx.x;
    const int lane = tid & 63;
    const int wid  = tid >> 6;
    const int wm   = wid >> 1;
    const int wn   = wid & 1;
    const int bx   = blockIdx.x % (NDIM / 128);
    const int by   = blockIdx.x / (NDIM / 128);

    const int srow   = tid >> 4;
    const int schunk = tid & 15;

    if (tid < 128) {
        xs_s[tid] = xsc[by * 128 + tid];
    } else {
        int n = tid - 128;
        ws_s[n] = wsc[bx * 128 + n];
        bs_s[n] = bias[bx * 128 + n];
    }

    const int* gA = xq + (size_t)(by * 128 + srow) * KW + schunk * 4;
    const int* gB = wq + (size_t)(bx * 128 + srow) * KW + schunk * 4;
    char* lA = As + srow * 144 + schunk * 8;
    char* lB = Bs + srow * 144 + schunk * 8;

    v4i acc[4][4];
#pragma unroll
    for (int i = 0; i < 4; ++i)
#pragma unroll
        for (int j = 0; j < 4; ++j) acc[i][j] = (v4i){0, 0, 0, 0};

    const int lr = lane & 15;
    const int lkb = (lane >> 4) * 16;

    for (int kt = 0; kt < KDIM / 128; ++kt) {
#pragma unroll
        for (int p = 0; p < 8; ++p) {
            v4i w = *(const v4i*)(gA + (size_t)p * 16 * KW + kt * 64);
            int lo8, hi8;
            unpack_w(w, lo8, hi8);
            *(v2i*)(lA + p * 16 * 144) = (v2i){lo8, hi8};
        }
#pragma unroll
        for (int p = 0; p < 8; ++p) {
            v4i w = *(const v4i*)(gB + (size_t)p * 16 * KW + kt * 64);
            int lo8, hi8;
            unpack_w(w, lo8, hi8);
            *(v2i*)(lB + p * 16 * 144) = (v2i){lo8, hi8};
        }
        __syncthreads();
#pragma unroll
        for (int ks = 0; ks < 2; ++ks) {
            v4i av[4], bv[4];
#pragma unroll
            for (int i = 0; i < 4; ++i)
                av[i] = *(const v4i*)(As + (wm * 64 + i * 16 + lr) * 144 + ks * 64 + lkb);
#pragma unroll
            for (int j = 0; j < 4; ++j)
                bv[j] = *(const v4i*)(Bs + (wn * 64 + j * 16 + lr) * 144 + ks * 64 + lkb);
#pragma unroll
            for (int i = 0; i < 4; ++i)
#pragma unroll
                for (int j = 0; j < 4; ++j)
                    acc[i][j] = __builtin_amdgcn_mfma_i32_16x16x64_i8(av[i], bv[j], acc[i][j], 0, 0, 0);
        }
        __syncthreads();
    }

    _Float16* Xh = (_Float16*)As;
    _Float16* Wh = (_Float16*)Bs;
#pragma unroll
    for (int p = 0; p < 8; ++p) {
        int row = p * 16 + srow;
        float4 vx = *(const float4*)(xr + (size_t)(by * 128 + row) * RDIM + schunk * 4);
        *(v4h*)(Xh + row * 72 + schunk * 4) =
            (v4h){(_Float16)vx.x, (_Float16)vx.y, (_Float16)vx.z, (_Float16)vx.w};
        float4 vw = *(const float4*)(wo + (size_t)(bx * 128 + row) * RDIM + schunk * 4);
        *(v4h*)(Wh + row * 72 + schunk * 4) =
            (v4h){(_Float16)vw.x, (_Float16)vw.y, (_Float16)vw.z, (_Float16)vw.w};
    }
    __syncthreads();

    v4f facc[4][4];
#pragma unroll
    for (int i = 0; i < 4; ++i)
#pragma unroll
        for (int j = 0; j < 4; ++j) facc[i][j] = (v4f){0.f, 0.f, 0.f, 0.f};

    const int lkh = (lane >> 4) * 8;
#pragma unroll
    for (int ks = 0; ks < 2; ++ks) {
        v8h ah[4], bh[4];
#pragma unroll
        for (int i = 0; i < 4; ++i)
            ah[i] = *(const v8h*)(Xh + (wm * 64 + i * 16 + lr) * 72 + ks * 32 + lkh);
#pragma unroll
        for (int j = 0; j < 4; ++j)
            bh[j] = *(const v8h*)(Wh + (wn * 64 + j * 16 + lr) * 72 + ks * 32 + lkh);
#pragma unroll
        for (int i = 0; i < 4; ++i)
#pragma unroll
            for (int j = 0; j < 4; ++j)
                facc[i][j] = __builtin_amdgcn_mfma_f32_16x16x32_f16(ah[i], bh[j], facc[i][j], 0, 0, 0);
    }

#pragma unroll
    for (int i = 0; i < 4; ++i) {
        int row0 = wm * 64 + i * 16 + (lane >> 4) * 4;
#pragma unroll
        for (int j = 0; j < 4; ++j) {
            int col = wn * 64 + j * 16 + lr;
            float sw = ws_s[col];
            float bz = bs_s[col];
#pragma unroll
            for (int r = 0; r < 4; ++r) {
                int row = row0 + r;
                float v = (float)acc[i][j][r] * xs_s[row] * sw + bz + facc[i][j][r];
                out[(size_t)(by * 128 + row) * NDIM + (bx * 128 + col)] = v;
            }
        }
    }
}

extern "C" void kernel_launch(void* const* d_in, const int* in_sizes, int n_in,
                              void* d_out, int out_size, void* d_ws, size_t ws_size,
                              hipStream_t stream) {
    const int*   xq   = (const int*)d_in[0];
    const float* xsc  = (const float*)d_in[1];
    const int*   wq   = (const int*)d_in[2];
    const float* wsc  = (const float*)d_in[3];
    const float* bias = (const float*)d_in[4];
    const float* xr   = (const float*)d_in[5];
    const float* wo   = (const float*)d_in[6];
    float* out = (float*)d_out;

    const size_t X8 = (size_t)MDIM * KDIM;   // 32 MiB
    const size_t W8 = (size_t)NDIM * KDIM;   // 16 MiB (tiled)

    if (ws_size >= X8 + W8) {
        char* x8  = (char*)d_ws;
        char* w8t = x8 + X8;
        repack_int4<<<2048, 256, 0, stream>>>(xq, wq, x8, w8t);
        w4a4_bl2<<<(MDIM / 256) * (NDIM / 256), 512, 0, stream>>>(
            x8, w8t, xsc, wsc, bias, xr, wo, out);
    } else {
        w4a4_fused<<<(MDIM / 128) * (NDIM / 128), 256, 0, stream>>>(
            xq, xsc, wq, wsc, bias, xr, wo, out);
    }
}

// Round 13
// 195.886 us; speedup vs baseline: 1.0025x; 1.0025x over previous
//
#include <hip/hip_runtime.h>
#include <hip/hip_fp16.h>

typedef int      v4i __attribute__((ext_vector_type(4)));
typedef int      v2i __attribute__((ext_vector_type(2)));
typedef float    v4f __attribute__((ext_vector_type(4)));
typedef _Float16 v8h __attribute__((ext_vector_type(8)));
typedef _Float16 v4h __attribute__((ext_vector_type(4)));

#define MDIM 8192
#define NDIM 4096
#define KDIM 4096
#define RDIM 64
#define KW   (KDIM / 2)
#define NT   (KDIM / 128)        // 32 K-tiles of BK=128 int8 (A staging units)

typedef const __attribute__((address_space(1))) char* gas_ptr;
typedef __attribute__((address_space(3))) char*       las_ptr;

__device__ __forceinline__ void unpack_w(v4i w, int& lo8, int& hi8) {
    unsigned p01 = __builtin_amdgcn_perm((unsigned)w.y, (unsigned)w.x, 0x0C0C0400u);
    unsigned p23 = __builtin_amdgcn_perm((unsigned)w.w, (unsigned)w.z, 0x0C0C0400u);
    unsigned b4  = __builtin_amdgcn_perm(p23, p01, 0x05040100u);
    unsigned lo = b4 & 0x0F0F0F0Fu;
    unsigned hi = (b4 >> 4) & 0x0F0F0F0Fu;
    lo8 = (int)(((lo ^ 0x08080808u) + 0x78787878u) ^ 0x80808080u);
    hi8 = (int)(((hi ^ 0x08080808u) + 0x78787878u) ^ 0x80808080u);
}

// ---- kernel 1: repack. x -> linear int8 rows. w -> lane-major MFMA tiles:
// [n/16 tile][k64 block][lane 0..63][16B], lane l holds col (l&15),
// k = k64*64 + (l>>4)*16 .. +16 -> a B fragment load is 1KB contiguous/wave.
__global__ __launch_bounds__(256)
void repack_int4(const int* __restrict__ xq, const int* __restrict__ wq,
                 char* __restrict__ x8, char* __restrict__ w8t)
{
    const size_t XCH = (size_t)MDIM * KW / 4;
    const size_t TCH = XCH + (size_t)NDIM * KW / 4;
    size_t stride = (size_t)gridDim.x * blockDim.x;
    for (size_t i = (size_t)blockIdx.x * blockDim.x + threadIdx.x; i < TCH; i += stride) {
        v4i w;
        char* dst;
        if (i < XCH) {
            w = *(const v4i*)(xq + i * 4);
            dst = x8 + i * 8;
        } else {
            size_t j = i - XCH;
            w = *(const v4i*)(wq + j * 4);
            int n  = (int)(j >> 9);      // 512 chunks (8 int4 each) per row
            int kc = (int)(j & 511);
            size_t block = (size_t)(n >> 4) * 64 + (kc >> 3);
            int lane = ((kc >> 1) & 3) * 16 + (n & 15);
            dst = w8t + block * 1024 + lane * 16 + (kc & 1) * 8;
        }
        int lo8, hi8;
        unpack_w(w, lo8, hi8);
        *(v2i*)dst = (v2i){lo8, hi8};
    }
}

// ---- kernel 2: 256x256 int8 GEMM, A via LDS, B via L2->registers ----------
// r5 skeleton (merged 4-phase, A [2][2] rotation, 1 barrier/phase) with B
// off the LDS port: LDS traffic/phase 128KB -> 80KB (< MFMA leg), LDS 67KB
// -> 2 blocks/CU (16 waves) for cross-block overlap.
__device__ __forceinline__ void stage2A(const char* g, char* l, int kt, int ks) {
    const char* s = g + kt * 128 + ks * 64;
    __builtin_amdgcn_global_load_lds((gas_ptr)(const void*)s,
                                     (las_ptr)(void*)l, 16, 0, 0);
    __builtin_amdgcn_global_load_lds((gas_ptr)(const void*)(s + (size_t)128 * KDIM),
                                     (las_ptr)(void*)(l + 8192), 16, 0, 0);
}

#define BAR asm volatile("s_barrier" ::: "memory")
#define VM6 asm volatile("s_waitcnt vmcnt(6)" ::: "memory")
#define SGB(m, n) __builtin_amdgcn_sched_group_barrier(m, n, 0)

// weave: 6 VMEM (4 B-loads + 2 A-DMA) early, 8 DS_READ laced, rest MFMA
#define SGBSEQ do {                                                            \
    SGB(0x30, 2); SGB(0x8, 2); SGB(0x30, 2); SGB(0x8, 2);                      \
    SGB(0x30, 2); SGB(0x8, 2);                                                 \
    SGB(0x100, 2); SGB(0x8, 4); SGB(0x100, 2); SGB(0x8, 4);                    \
    SGB(0x100, 2); SGB(0x8, 4); SGB(0x100, 2); SGB(0x8, 4);                    \
    SGB(0x8, 10);                                                              \
} while (0)

#define READ_A8(dst, PAR, KS)                                                  \
    _Pragma("unroll")                                                          \
    for (int ii = 0; ii < 8; ++ii)                                             \
        dst[ii] = *(const v4i*)((const char*)Asub[PAR][KS] + aoff + ii * 1024)

#define LOADB4(dst, K64)                                                       \
    _Pragma("unroll")                                                          \
    for (int jj = 0; jj < 4; ++jj)                                             \
        dst[jj] = *(const v4i*)(gBb + (size_t)jj * 65536 + (size_t)(K64) * 1024)

#define MMA32(AS, BS)                                                          \
    _Pragma("unroll")                                                          \
    for (int ii = 0; ii < 8; ++ii)                                             \
        _Pragma("unroll")                                                      \
        for (int jj = 0; jj < 4; ++jj)                                         \
            acc[ii][jj] = __builtin_amdgcn_mfma_i32_16x16x64_i8(               \
                AS[ii], BS[jj], acc[ii][jj], 0, 0, 0)

// FIFO ledger (per wave; order B4 then A2): entering phase P the queue is
// [B(P)4][A(P-1)2]. Compiler auto-waits the B registers before MMA; manual
// VM6 at phase end leaves [B(P+1)4][A(P)2] -> A(P-1) drained before its
// ds_read at phase P+1. Verified through prologue and steady state.
#define QPHASE(CA, CB, NA, NB, NPAR, NKS, SPAR, SKS, SKT, KB) do {             \
    LOADB4(NB, KB);                                                            \
    stage2A(gA, &Asub[SPAR][SKS][ldsW], SKT, SKS);                             \
    READ_A8(NA, NPAR, NKS);                                                    \
    MMA32(CA, CB);                                                             \
    SGBSEQ;                                                                    \
    VM6; BAR;                                                                  \
} while (0)

__global__ __launch_bounds__(512, 2)
void w4a4_bl2(const char* __restrict__ x8, const char* __restrict__ w8t,
              const float* __restrict__ xsc, const float* __restrict__ wsc,
              const float* __restrict__ bias, const float* __restrict__ xr,
              const float* __restrict__ wo, float* __restrict__ out)
{
    // A only: [parity][k-half][256 rows x 64B], swizzled: byte c of row r
    // holds global col c ^ (((r>>1)&3)<<4). 64 KiB + 3 KiB -> 2 blocks/CU.
    __shared__ __align__(16) char Asub[2][2][16384];
    __shared__ float xs_s[256];
    __shared__ float ws_s[256];
    __shared__ float bs_s[256];

    const int tid  = threadIdx.x;
    const int lane = tid & 63;
    const int wid  = tid >> 6;     // 0..7
    const int wm   = wid >> 2;     // M half (0..1)
    const int wn   = wid & 3;      // N quarter (0..3)

    // XCD-grouped bijective swizzle: each XCD owns 2 B column-panels (2MB,
    // L2-resident) and sweeps 32 M-panels within each.
    const int xcd = blockIdx.x & 7;
    const int seq = blockIdx.x >> 3;          // 0..63
    const int bxn = xcd * 2 + (seq >> 5);     // 0..15
    const int by  = seq & 31;                 // 0..31

    if (tid < 256) {
        xs_s[tid] = xsc[by * 256 + tid];
    } else {
        int n = tid - 256;
        ws_s[n] = wsc[bxn * 256 + n];
        bs_s[n] = bias[bxn * 256 + n];
    }

    // A staging: lane covers 16B of row (wid*16 + lane/4), pre-swizzled col
    const int srow = wid * 16 + (lane >> 2);
    const int scol = ((lane & 3) * 16) ^ (((lane >> 3) & 3) << 4);
    const char* gA = x8 + (size_t)(by * 256 + srow) * KDIM + scol;
    const int ldsW = wid * 1024;

    // B: lane-major tiled layout; wave's 4 n-tiles start at t0
    const char* gBb = w8t + (size_t)(bxn * 16 + wn * 4) * 65536 + lane * 16;

    // A fragment read geometry (16x16x64; swizzle XOR lane-constant)
    const int lr   = lane & 15;
    const int cef  = ((lane >> 4) << 4) ^ (((lr >> 1) & 3) << 4);
    const int aoff = (wm * 128 + lr) * 64 + cef;

    v4i acc[8][4];
#pragma unroll
    for (int i = 0; i < 8; ++i)
#pragma unroll
        for (int j = 0; j < 4; ++j) acc[i][j] = (v4i){0, 0, 0, 0};

    v4i a0[8], a1[8], b0[4], b1[4];

    // prologue: A stages (6 events) then B0 (4); vmcnt(6) drains A00,A01
    // leaving [A10·2? -> no: leaves B0·4 + A10·2] == steady-state pattern.
    stage2A(gA, &Asub[0][0][ldsW], 0, 0);
    stage2A(gA, &Asub[0][1][ldsW], 0, 1);
    LOADB4(b0, 0);
    stage2A(gA, &Asub[1][0][ldsW], 1, 0);
    VM6; BAR;
    READ_A8(a0, 0, 0);

    // A rotation identical to r5 (staged Qi, read Qi+3). B k64 index per
    // phase = the k-window of the NEXT phase's compute; tail clamps to 63
    // (dead loads, uniform counts).
    for (int it = 0; it < NT / 2; ++it) {
        const int kt1 = 2 * it + 1;
        const int kt2 = (2 * it + 2 < NT) ? 2 * it + 2 : NT - 1;
        const int kt3 = (2 * it + 3 < NT) ? 2 * it + 3 : NT - 1;
        const int kb4 = (4 * it + 4 < 64) ? 4 * it + 4 : 63;
        // Q1: compute [0][0] (k64=4it, B=b0); next frags from [0][1]
        QPHASE(a0, b0, a1, b1, 0, 1, 1, 1, kt1, 4 * it + 1);
        // Q2: compute [0][1]; next from [1][0]
        QPHASE(a1, b1, a0, b0, 1, 0, 0, 0, kt2, 4 * it + 2);
        // Q3: compute [1][0]; next from [1][1]
        QPHASE(a0, b0, a1, b1, 1, 1, 0, 1, kt2, 4 * it + 3);
        // Q4: compute [1][1]; next from [0][0] (restaged @kt2)
        QPHASE(a1, b1, a0, b0, 0, 0, 1, 0, kt3, kb4);
    }

    // drain DMAs before overwriting LDS with the f16 outlier tiles
    asm volatile("s_waitcnt vmcnt(0)" ::: "memory");
    BAR;

    // ---- rank-64 outlier staging: f16 [256][64] (128B rows), XOR-swizzled
    // byte ^= ((row&7)<<4). Xh = Asub bytes 0..32K, Wh = 32K..64K.
    char* Xh = (char*)&Asub[0][0][0];
    char* Wh = Xh + 32768;
    {
        const int rr = tid >> 3;          // 0..63
        const int cb = (tid & 7) * 16;    // byte col within 128B row
#pragma unroll
        for (int p = 0; p < 4; ++p) {
            const int row = p * 64 + rr;
            const int sw = cb ^ ((row & 7) << 4);
            v4f x0 = *(const v4f*)(xr + (size_t)(by * 256 + row) * RDIM + (cb >> 1));
            v4f x1 = *(const v4f*)(xr + (size_t)(by * 256 + row) * RDIM + (cb >> 1) + 4);
            v8h hx = {(_Float16)x0[0], (_Float16)x0[1], (_Float16)x0[2], (_Float16)x0[3],
                      (_Float16)x1[0], (_Float16)x1[1], (_Float16)x1[2], (_Float16)x1[3]};
            *(v8h*)(Xh + (size_t)row * 128 + sw) = hx;
            v4f w0 = *(const v4f*)(wo + (size_t)(bxn * 256 + row) * RDIM + (cb >> 1));
            v4f w1 = *(const v4f*)(wo + (size_t)(bxn * 256 + row) * RDIM + (cb >> 1) + 4);
            v8h hw = {(_Float16)w0[0], (_Float16)w0[1], (_Float16)w0[2], (_Float16)w0[3],
                      (_Float16)w1[0], (_Float16)w1[1], (_Float16)w1[2], (_Float16)w1[3]};
            *(v8h*)(Wh + (size_t)row * 128 + sw) = hw;
        }
    }

    // dequant in place (int acc -> f32 bits), overlaps the LDS staging above
#pragma unroll
    for (int i = 0; i < 8; ++i) {
        const int r0 = wm * 128 + i * 16 + ((lane >> 4) << 2);
        const v4f xs4 = *(const v4f*)&xs_s[r0];
#pragma unroll
        for (int j = 0; j < 4; ++j) {
            const int col = wn * 64 + j * 16 + lr;
            const float sw = ws_s[col];
            const float bz = bs_s[col];
            v4f f;
#pragma unroll
            for (int r = 0; r < 4; ++r)
                f[r] = (float)acc[i][j][r] * xs4[r] * sw + bz;
            acc[i][j] = __builtin_bit_cast(v4i, f);
        }
    }
    __syncthreads();

    // rank-64 outlier, f16 MFMA accumulating into the dequantized f32 frags
#pragma unroll
    for (int ks = 0; ks < 2; ++ks) {
        v8h ah[8], bh[4];
#pragma unroll
        for (int i = 0; i < 8; ++i) {
            const int row = wm * 128 + i * 16 + lr;
            const int c   = (ks * 64 + ((lane >> 4) << 4)) ^ ((row & 7) << 4);
            ah[i] = *(const v8h*)(Xh + (size_t)row * 128 + c);
        }
#pragma unroll
        for (int j = 0; j < 4; ++j) {
            const int row = wn * 64 + j * 16 + lr;
            const int c   = (ks * 64 + ((lane >> 4) << 4)) ^ ((row & 7) << 4);
            bh[j] = *(const v8h*)(Wh + (size_t)row * 128 + c);
        }
#pragma unroll
        for (int i = 0; i < 8; ++i)
#pragma unroll
            for (int j = 0; j < 4; ++j) {
                v4f c = __builtin_bit_cast(v4f, acc[i][j]);
                c = __builtin_amdgcn_mfma_f32_16x16x32_f16(ah[i], bh[j], c, 0, 0, 0);
                acc[i][j] = __builtin_bit_cast(v4i, c);
            }
    }

    const size_t obase = (size_t)(by * 256 + wm * 128 + ((lane >> 4) << 2)) * NDIM
                       + bxn * 256 + wn * 64 + lr;
#pragma unroll
    for (int i = 0; i < 8; ++i)
#pragma unroll
        for (int j = 0; j < 4; ++j) {
            v4f f = __builtin_bit_cast(v4f, acc[i][j]);
#pragma unroll
            for (int r = 0; r < 4; ++r)
                out[obase + (size_t)(i * 16 + r) * NDIM + j * 16] = f[r];
        }
}

// ---------------- fallback: fused single-kernel path (ws too small) --------
__global__ __launch_bounds__(256, 2)
void w4a4_fused(const int* __restrict__ xq, const float* __restrict__ xsc,
                const int* __restrict__ wq, const float* __restrict__ wsc,
                const float* __restrict__ bias, const float* __restrict__ xr,
                const float* __restrict__ wo, float* __restrict__ out)
{
    __shared__ __align__(16) char As[128 * 144];
    __shared__ __align__(16) char Bs[128 * 144];
    __shared__ float xs_s[128];
    __shared__ float ws_s[128];
    __shared__ float bs_s[128];

    const int tid  = threadIdx.x;
    const int lane = tid & 63;
    const int wid  = tid >> 6;
    const int wm   = wid >> 1;
    const int wn   = wid & 1;
    const int bx   = blockIdx.x % (NDIM / 128);
    const int by   = blockIdx.x / (NDIM / 128);

    const int srow   = tid >> 4;
    const int schunk = tid & 15;

    if (tid < 128) {
        xs_s[tid] = xsc[by * 128 + tid];
    } else {
        int n = tid - 128;
        ws_s[n] = wsc[bx * 128 + n];
        bs_s[n] = bias[bx * 128 + n];
    }

    const int* gA = xq + (size_t)(by * 128 + srow) * KW + schunk * 4;
    const int* gB = wq + (size_t)(bx * 128 + srow) * KW + schunk * 4;
    char* lA = As + srow * 144 + schunk * 8;
    char* lB = Bs + srow * 144 + schunk * 8;

    v4i acc[4][4];
#pragma unroll
    for (int i = 0; i < 4; ++i)
#pragma unroll
        for (int j = 0; j < 4; ++j) acc[i][j] = (v4i){0, 0, 0, 0};

    const int lr = lane & 15;
    const int lkb = (lane >> 4) * 16;

    for (int kt = 0; kt < KDIM / 128; ++kt) {
#pragma unroll
        for (int p = 0; p < 8; ++p) {
            v4i w = *(const v4i*)(gA + (size_t)p * 16 * KW + kt * 64);
            int lo8, hi8;
            unpack_w(w, lo8, hi8);
            *(v2i*)(lA + p * 16 * 144) = (v2i){lo8, hi8};
        }
#pragma unroll
        for (int p = 0; p < 8; ++p) {
            v4i w = *(const v4i*)(gB + (size_t)p * 16 * KW + kt * 64);
            int lo8, hi8;
            unpack_w(w, lo8, hi8);
            *(v2i*)(lB + p * 16 * 144) = (v2i){lo8, hi8};
        }
        __syncthreads();
#pragma unroll
        for (int ks = 0; ks < 2; ++ks) {
            v4i av[4], bv[4];
#pragma unroll
            for (int i = 0; i < 4; ++i)
                av[i] = *(const v4i*)(As + (wm * 64 + i * 16 + lr) * 144 + ks * 64 + lkb);
#pragma unroll
            for (int j = 0; j < 4; ++j)
                bv[j] = *(const v4i*)(Bs + (wn * 64 + j * 16 + lr) * 144 + ks * 64 + lkb);
#pragma unroll
            for (int i = 0; i < 4; ++i)
#pragma unroll
                for (int j = 0; j < 4; ++j)
                    acc[i][j] = __builtin_amdgcn_mfma_i32_16x16x64_i8(av[i], bv[j], acc[i][j], 0, 0, 0);
        }
        __syncthreads();
    }

    _Float16* Xh = (_Float16*)As;
    _Float16* Wh = (_Float16*)Bs;
#pragma unroll
    for (int p = 0; p < 8; ++p) {
        int row = p * 16 + srow;
        float4 vx = *(const float4*)(xr + (size_t)(by * 128 + row) * RDIM + schunk * 4);
        *(v4h*)(Xh + row * 72 + schunk * 4) =
            (v4h){(_Float16)vx.x, (_Float16)vx.y, (_Float16)vx.z, (_Float16)vx.w};
        float4 vw = *(const float4*)(wo + (size_t)(bx * 128 + row) * RDIM + schunk * 4);
        *(v4h*)(Wh + row * 72 + schunk * 4) =
            (v4h){(_Float16)vw.x, (_Float16)vw.y, (_Float16)vw.z, (_Float16)vw.w};
    }
    __syncthreads();

    v4f facc[4][4];
#pragma unroll
    for (int i = 0; i < 4; ++i)
#pragma unroll
        for (int j = 0; j < 4; ++j) facc[i][j] = (v4f){0.f, 0.f, 0.f, 0.f};

    const int lkh = (lane >> 4) * 8;
#pragma unroll
    for (int ks = 0; ks < 2; ++ks) {
        v8h ah[4], bh[4];
#pragma unroll
        for (int i = 0; i < 4; ++i)
            ah[i] = *(const v8h*)(Xh + (wm * 64 + i * 16 + lr) * 72 + ks * 32 + lkh);
#pragma unroll
        for (int j = 0; j < 4; ++j)
            bh[j] = *(const v8h*)(Wh + (wn * 64 + j * 16 + lr) * 72 + ks * 32 + lkh);
#pragma unroll
        for (int i = 0; i < 4; ++i)
#pragma unroll
            for (int j = 0; j < 4; ++j)
                facc[i][j] = __builtin_amdgcn_mfma_f32_16x16x32_f16(ah[i], bh[j], facc[i][j], 0, 0, 0);
    }

#pragma unroll
    for (int i = 0; i < 4; ++i) {
        int row0 = wm * 64 + i * 16 + (lane >> 4) * 4;
#pragma unroll
        for (int j = 0; j < 4; ++j) {
            int col = wn * 64 + j * 16 + lr;
            float sw = ws_s[col];
            float bz = bs_s[col];
#pragma unroll
            for (int r = 0; r < 4; ++r) {
                int row = row0 + r;
                float v = (float)acc[i][j][r] * xs_s[row] * sw + bz + facc[i][j][r];
                out[(size_t)(by * 128 + row) * NDIM + (bx * 128 + col)] = v;
            }
        }
    }
}

extern "C" void kernel_launch(void* const* d_in, const int* in_sizes, int n_in,
                              void* d_out, int out_size, void* d_ws, size_t ws_size,
                              hipStream_t stream) {
    const int*   xq   = (const int*)d_in[0];
    const float* xsc  = (const float*)d_in[1];
    const int*   wq   = (const int*)d_in[2];
    const float* wsc  = (const float*)d_in[3];
    const float* bias = (const float*)d_in[4];
    const float* xr   = (const float*)d_in[5];
    const float* wo   = (const float*)d_in[6];
    float* out = (float*)d_out;

    const size_t X8 = (size_t)MDIM * KDIM;   // 32 MiB
    const size_t W8 = (size_t)NDIM * KDIM;   // 16 MiB (tiled)

    if (ws_size >= X8 + W8) {
        char* x8  = (char*)d_ws;
        char* w8t = x8 + X8;
        repack_int4<<<2048, 256, 0, stream>>>(xq, wq, x8, w8t);
        w4a4_bl2<<<(MDIM / 256) * (NDIM / 256), 512, 0, stream>>>(
            x8, w8t, xsc, wsc, bias, xr, wo, out);
    } else {
        w4a4_fused<<<(MDIM / 128) * (NDIM / 128), 256, 0, stream>>>(
            xq, xsc, wq, wsc, bias, xr, wo, out);
    }
}

// Round 14
// 175.359 us; speedup vs baseline: 1.1199x; 1.1171x over previous
//
#include <hip/hip_runtime.h>
#include <hip/hip_fp16.h>

typedef int      v4i  __attribute__((ext_vector_type(4)));
typedef int      v2i  __attribute__((ext_vector_type(2)));
typedef int      v16i __attribute__((ext_vector_type(16)));
typedef float    v4f  __attribute__((ext_vector_type(4)));
typedef float    v16f __attribute__((ext_vector_type(16)));
typedef _Float16 v8h  __attribute__((ext_vector_type(8)));
typedef _Float16 v4h  __attribute__((ext_vector_type(4)));

#define MDIM 8192
#define NDIM 4096
#define KDIM 4096
#define RDIM 64
#define KW   (KDIM / 2)
#define NT   (KDIM / 128)        // 32 K-tiles of BK=128 int8

typedef const __attribute__((address_space(1))) char* gas_ptr;
typedef __attribute__((address_space(3))) char*       las_ptr;

__device__ __forceinline__ void unpack_w(v4i w, int& lo8, int& hi8) {
    unsigned p01 = __builtin_amdgcn_perm((unsigned)w.y, (unsigned)w.x, 0x0C0C0400u);
    unsigned p23 = __builtin_amdgcn_perm((unsigned)w.w, (unsigned)w.z, 0x0C0C0400u);
    unsigned b4  = __builtin_amdgcn_perm(p23, p01, 0x05040100u);
    unsigned lo = b4 & 0x0F0F0F0Fu;
    unsigned hi = (b4 >> 4) & 0x0F0F0F0Fu;
    lo8 = (int)(((lo ^ 0x08080808u) + 0x78787878u) ^ 0x80808080u);
    hi8 = (int)(((hi ^ 0x08080808u) + 0x78787878u) ^ 0x80808080u);
}

// ---------------- kernel 1: repack packed-int32 nibbles -> dense int8 -------
__global__ __launch_bounds__(256)
void repack_int4(const int* __restrict__ xq, const int* __restrict__ wq,
                 char* __restrict__ x8, char* __restrict__ w8)
{
    const size_t XCH = (size_t)MDIM * KW / 4;
    const size_t TCH = XCH + (size_t)NDIM * KW / 4;
    size_t stride = (size_t)gridDim.x * blockDim.x;
    for (size_t i = (size_t)blockIdx.x * blockDim.x + threadIdx.x; i < TCH; i += stride) {
        const int* src;
        char* dst;
        if (i < XCH) { src = xq + i * 4; dst = x8 + i * 8; }
        else { size_t j = i - XCH; src = wq + j * 4; dst = w8 + j * 8; }
        v4i w = *(const v4i*)src;
        int lo8, hi8;
        unpack_w(w, lo8, hi8);
        *(v2i*)dst = (v2i){lo8, hi8};
    }
}

// ---- kernel 2: 256x256 int8 GEMM, 32x32x32 MFMA, [256][128B] swizzled LDS --
// Layout: row r, byte c stored at c ^ ((r&7)<<4) within the 128B row ->
// 32-lane same-column fragment reads hit all 32 banks (conflict-free; G4).
// Rotation: sub(P,0) stages B(P+1); sub(P,1) stages A(P+2); VM0 before every
// sub-end barrier certifies all outstanding DMAs (latency hidden by the
// ~2400-cyc sub). Frag ping-pong read-ahead by one sub.
__device__ __forceinline__ void stage4(const char* g, char* l, int kt) {
#pragma unroll
    for (int q = 0; q < 4; ++q)
        __builtin_amdgcn_global_load_lds(
            (gas_ptr)(const void*)(g + (size_t)(q * 8) * KDIM + kt * 128),
            (las_ptr)(void*)(l + q * 1024), 16, 0, 0);
}

#define BAR   asm volatile("s_barrier" ::: "memory")
#define VM0   asm volatile("s_waitcnt vmcnt(0)" ::: "memory")
#define LGKM0 do { asm volatile("s_waitcnt lgkmcnt(0)" ::: "memory");          \
                   __builtin_amdgcn_sched_barrier(0); } while (0)
#define SGB(m, n) __builtin_amdgcn_sched_group_barrier(m, n, 0)

// weave per sub: 4 VMEM (stage) + 12 DS_READ laced through 16 MFMA
#define SGBSEQ do {                                                            \
    SGB(0x30, 1); SGB(0x8, 1); SGB(0x30, 1); SGB(0x8, 1);                      \
    SGB(0x30, 1); SGB(0x8, 1); SGB(0x30, 1); SGB(0x8, 1);                      \
    SGB(0x100, 3); SGB(0x8, 3); SGB(0x100, 3); SGB(0x8, 3);                    \
    SGB(0x100, 3); SGB(0x8, 3); SGB(0x100, 3); SGB(0x8, 3);                    \
} while (0)

// read frags for (tile in buf PAR, k-half H): A 4 tiles x 2 ksteps, B 2 x 2
#define READF(FA, FB, PAR, H) do {                                             \
    const char* Ab_ = (const char*)Abuf[PAR];                                  \
    const char* Bb_ = (const char*)Bbuf[PAR];                                  \
    _Pragma("unroll")                                                          \
    for (int m_ = 0; m_ < 4; ++m_)                                             \
        _Pragma("unroll")                                                      \
        for (int ks_ = 0; ks_ < 2; ++ks_)                                      \
            FA[m_ * 2 + ks_] = *(const v4i*)(Ab_ + aoffM + m_ * 4096 +         \
                                   (((H) * 64 + ks_ * 32) ^ cef));             \
    _Pragma("unroll")                                                          \
    for (int j_ = 0; j_ < 2; ++j_)                                             \
        _Pragma("unroll")                                                      \
        for (int ks_ = 0; ks_ < 2; ++ks_)                                      \
            FB[j_ * 2 + ks_] = *(const v4i*)(Bb_ + boffN + j_ * 4096 +         \
                                   (((H) * 64 + ks_ * 32) ^ cef));             \
} while (0)

#define MMA16(FA, FB)                                                          \
    _Pragma("unroll")                                                          \
    for (int ks_ = 0; ks_ < 2; ++ks_)                                          \
        _Pragma("unroll")                                                      \
        for (int m_ = 0; m_ < 4; ++m_)                                         \
            _Pragma("unroll")                                                  \
            for (int j_ = 0; j_ < 2; ++j_)                                     \
                acc[m_][j_] = __builtin_amdgcn_mfma_i32_32x32x32_i8(           \
                    FA[m_ * 2 + ks_], FB[j_ * 2 + ks_], acc[m_][j_], 0, 0, 0)

__global__ __launch_bounds__(512, 2)
void w4a4_g32b(const char* __restrict__ x8, const char* __restrict__ w8,
               const float* __restrict__ xsc, const float* __restrict__ wsc,
               const float* __restrict__ bias, const float* __restrict__ xr,
               const float* __restrict__ wo, float* __restrict__ out)
{
    // [parity][256 rows x 128B], byte c of row r holds global col
    // c ^ ((r&7)<<4). 64KB + 64KB + 3KB scales = 131KB.
    __shared__ __align__(16) char Abuf[2][32768];
    __shared__ __align__(16) char Bbuf[2][32768];
    __shared__ float xs_s[256];
    __shared__ float ws_s[256];
    __shared__ float bs_s[256];

    const int tid  = threadIdx.x;
    const int lane = tid & 63;
    const int wid  = tid >> 6;     // 0..7
    const int wm   = wid >> 2;     // M half (0..1)
    const int wn   = wid & 3;      // N quarter (0..3)

    // bijective XCD swizzle: 512 blocks = 8 XCDs x 64
    const int s  = (blockIdx.x & 7) * 64 + (blockIdx.x >> 3);
    const int by = s >> 4;         // 0..31
    const int bxn = s & 15;        // 0..15

    if (tid < 256) {
        xs_s[tid] = xsc[by * 256 + tid];
    } else {
        int n = tid - 256;
        ws_s[n] = wsc[bxn * 256 + n];
        bs_s[n] = bias[bxn * 256 + n];
    }

    // staging: lane i writes LDS slot (row i>>3, 16B-chunk i&7) of its wave's
    // 32-row region; global source col pre-swizzled (rule #21 both-sides).
    const int scol = ((lane & 7) << 4) ^ (((lane >> 3) & 7) << 4);
    const char* gA = x8 + (size_t)(by * 256 + wid * 32 + (lane >> 3)) * KDIM + scol;
    const char* gB = w8 + (size_t)(bxn * 256 + wid * 32 + (lane >> 3)) * KDIM + scol;
    const int ldsW = wid * 4096;

    // fragment read geometry: A row = m*32 + l31 (rows of 128B), k-chunk 16B
    // at (H*64 + ks*32 + kh*16) ^ ((row&7)<<4); kh and row-swizzle folded
    // into lane-constant cef (disjoint-bit XOR).
    const int l31 = lane & 31;
    const int kh  = lane >> 5;     // 0..1
    const int cef  = (kh << 4) ^ ((l31 & 7) << 4);
    const int aoffM = wm * 16384 + l31 * 128;
    const int boffN = wn * 8192  + l31 * 128;

    v16i acc[4][2];
#pragma unroll
    for (int i = 0; i < 4; ++i)
#pragma unroll
        for (int j = 0; j < 2; ++j)
#pragma unroll
            for (int r = 0; r < 16; ++r) acc[i][j][r] = 0;

    // prologue: A0,B0 -> buf0; A1 -> buf1 (B1 staged in-loop at sub(0,0)).
    stage4(gA, &Abuf[0][ldsW], 0);
    stage4(gB, &Bbuf[0][ldsW], 0);
    stage4(gA, &Abuf[1][ldsW], 1);
    VM0; BAR;

    v4i f0A[8], f0B[4], f1A[8], f1B[4];
    READF(f0A, f0B, 0, 0);             // tile0, k-half 0
    LGKM0;                             // my buf0 reads done before sub(0,1)'s A-stage
    BAR;

    // Ledger: every sub ends VM0+BAR -> all DMAs staged this sub (and earlier)
    // are visible to every wave after the barrier. WAR: stages are delayed one
    // sub past the last reader of their region (verified P=0..2 + tail).
    for (int P = 0; P < NT; ++P) {
        const int ktB = (P + 1 < NT) ? P + 1 : NT - 1;
        const int ktA = (P + 2 < NT) ? P + 2 : NT - 1;
        // sub(P,0): compute (P,h0); read (P,h1); stage B(P+1)->buf[(P+1)&1]
        stage4(gB, &Bbuf[(P + 1) & 1][ldsW], ktB);
        READF(f1A, f1B, P & 1, 1);
        MMA16(f0A, f0B);
        SGBSEQ;
        LGKM0; VM0; BAR;
        // sub(P,1): compute (P,h1); read (P+1,h0); stage A(P+2)->buf[P&1]
        stage4(gA, &Abuf[P & 1][ldsW], ktA);
        READF(f0A, f0B, (P + 1) & 1, 0);
        MMA16(f1A, f1B);
        SGBSEQ;
        LGKM0; VM0; BAR;
    }

    // loop already ended VM0+BAR; LDS free for the f16 outlier tiles
    char* Xh = (char*)&Abuf[0][0];     // f16 [256][64] in 128B rows, swizzled
    char* Wh = (char*)&Bbuf[0][0];
    {
        const int rr = tid >> 3;          // 0..63
        const int cb = (tid & 7) * 16;    // byte col within 128B row
#pragma unroll
        for (int p = 0; p < 4; ++p) {
            const int row = p * 64 + rr;
            const int sw = cb ^ ((row & 7) << 4);
            v4f x0 = *(const v4f*)(xr + (size_t)(by * 256 + row) * RDIM + (cb >> 1));
            v4f x1 = *(const v4f*)(xr + (size_t)(by * 256 + row) * RDIM + (cb >> 1) + 4);
            v8h hx = {(_Float16)x0[0], (_Float16)x0[1], (_Float16)x0[2], (_Float16)x0[3],
                      (_Float16)x1[0], (_Float16)x1[1], (_Float16)x1[2], (_Float16)x1[3]};
            *(v8h*)(Xh + (size_t)row * 128 + sw) = hx;
            v4f w0 = *(const v4f*)(wo + (size_t)(bxn * 256 + row) * RDIM + (cb >> 1));
            v4f w1 = *(const v4f*)(wo + (size_t)(bxn * 256 + row) * RDIM + (cb >> 1) + 4);
            v8h hw = {(_Float16)w0[0], (_Float16)w0[1], (_Float16)w0[2], (_Float16)w0[3],
                      (_Float16)w1[0], (_Float16)w1[1], (_Float16)w1[2], (_Float16)w1[3]};
            *(v8h*)(Wh + (size_t)row * 128 + sw) = hw;
        }
    }

    // dequant in place (int acc -> f32 bits); 32x32 C layout (r10-validated):
    // col = l31, row_in_tile = (r&3) + 8*(r>>2) + 4*kh
#pragma unroll
    for (int i = 0; i < 4; ++i) {
        const int r0 = wm * 128 + i * 32 + kh * 4;
#pragma unroll
        for (int j = 0; j < 2; ++j) {
            const int col = wn * 64 + j * 32 + l31;
            const float sw = ws_s[col];
            const float bz = bs_s[col];
            v16f f;
#pragma unroll
            for (int q = 0; q < 4; ++q) {
                const v4f xs4 = *(const v4f*)&xs_s[r0 + q * 8];
#pragma unroll
                for (int r = 0; r < 4; ++r)
                    f[q * 4 + r] = (float)acc[i][j][q * 4 + r] * xs4[r] * sw + bz;
            }
            acc[i][j] = __builtin_bit_cast(v16i, f);
        }
    }
    __syncthreads();

    // rank-64 outlier: f32_32x32x16_f16, 4 ksteps over R=64 (r10-validated)
    const int obsw = (kh << 4) ^ ((l31 & 7) << 4);
#pragma unroll
    for (int ks = 0; ks < 4; ++ks) {
        v8h ah[4], bh[2];
#pragma unroll
        for (int i = 0; i < 4; ++i) {
            const int row = wm * 128 + i * 32 + l31;
            ah[i] = *(const v8h*)(Xh + (size_t)row * 128 + (obsw ^ (ks << 5)));
        }
#pragma unroll
        for (int j = 0; j < 2; ++j) {
            const int row = wn * 64 + j * 32 + l31;
            bh[j] = *(const v8h*)(Wh + (size_t)row * 128 + (obsw ^ (ks << 5)));
        }
#pragma unroll
        for (int i = 0; i < 4; ++i)
#pragma unroll
            for (int j = 0; j < 2; ++j) {
                v16f c = __builtin_bit_cast(v16f, acc[i][j]);
                c = __builtin_amdgcn_mfma_f32_32x32x16_f16(ah[i], bh[j], c, 0, 0, 0);
                acc[i][j] = __builtin_bit_cast(v16i, c);
            }
    }

    // ---- store (32x32 C layout) ----
    const int colb = bxn * 256 + wn * 64 + l31;
    const int rowb = by * 256 + wm * 128 + kh * 4;
#pragma unroll
    for (int i = 0; i < 4; ++i)
#pragma unroll
        for (int j = 0; j < 2; ++j) {
            v16f f = __builtin_bit_cast(v16f, acc[i][j]);
            const int col = colb + j * 32;
#pragma unroll
            for (int q = 0; q < 4; ++q) {
                const int row = rowb + i * 32 + q * 8;
#pragma unroll
                for (int r = 0; r < 4; ++r)
                    out[(size_t)(row + r) * NDIM + col] = f[q * 4 + r];
            }
        }
}

// ---------------- fallback: fused single-kernel path (ws too small) --------
__global__ __launch_bounds__(256, 2)
void w4a4_fused(const int* __restrict__ xq, const float* __restrict__ xsc,
                const int* __restrict__ wq, const float* __restrict__ wsc,
                const float* __restrict__ bias, const float* __restrict__ xr,
                const float* __restrict__ wo, float* __restrict__ out)
{
    __shared__ __align__(16) char As[128 * 144];
    __shared__ __align__(16) char Bs[128 * 144];
    __shared__ float xs_s[128];
    __shared__ float ws_s[128];
    __shared__ float bs_s[128];

    const int tid  = threadIdx.x;
    const int lane = tid & 63;
    const int wid  = tid >> 6;
    const int wm   = wid >> 1;
    const int wn   = wid & 1;
    const int bx   = blockIdx.x % (NDIM / 128);
    const int by   = blockIdx.x / (NDIM / 128);

    const int srow   = tid >> 4;
    const int schunk = tid & 15;

    if (tid < 128) {
        xs_s[tid] = xsc[by * 128 + tid];
    } else {
        int n = tid - 128;
        ws_s[n] = wsc[bx * 128 + n];
        bs_s[n] = bias[bx * 128 + n];
    }

    const int* gA = xq + (size_t)(by * 128 + srow) * KW + schunk * 4;
    const int* gB = wq + (size_t)(bx * 128 + srow) * KW + schunk * 4;
    char* lA = As + srow * 144 + schunk * 8;
    char* lB = Bs + srow * 144 + schunk * 8;

    v4i acc[4][4];
#pragma unroll
    for (int i = 0; i < 4; ++i)
#pragma unroll
        for (int j = 0; j < 4; ++j) acc[i][j] = (v4i){0, 0, 0, 0};

    const int lr = lane & 15;
    const int lkb = (lane >> 4) * 16;

    for (int kt = 0; kt < KDIM / 128; ++kt) {
#pragma unroll
        for (int p = 0; p < 8; ++p) {
            v4i w = *(const v4i*)(gA + (size_t)p * 16 * KW + kt * 64);
            int lo8, hi8;
            unpack_w(w, lo8, hi8);
            *(v2i*)(lA + p * 16 * 144) = (v2i){lo8, hi8};
        }
#pragma unroll
        for (int p = 0; p < 8; ++p) {
            v4i w = *(const v4i*)(gB + (size_t)p * 16 * KW + kt * 64);
            int lo8, hi8;
            unpack_w(w, lo8, hi8);
            *(v2i*)(lB + p * 16 * 144) = (v2i){lo8, hi8};
        }
        __syncthreads();
#pragma unroll
        for (int ks = 0; ks < 2; ++ks) {
            v4i av[4], bv[4];
#pragma unroll
            for (int i = 0; i < 4; ++i)
                av[i] = *(const v4i*)(As + (wm * 64 + i * 16 + lr) * 144 + ks * 64 + lkb);
#pragma unroll
            for (int j = 0; j < 4; ++j)
                bv[j] = *(const v4i*)(Bs + (wn * 64 + j * 16 + lr) * 144 + ks * 64 + lkb);
#pragma unroll
            for (int i = 0; i < 4; ++i)
#pragma unroll
                for (int j = 0; j < 4; ++j)
                    acc[i][j] = __builtin_amdgcn_mfma_i32_16x16x64_i8(av[i], bv[j], acc[i][j], 0, 0, 0);
        }
        __syncthreads();
    }

    _Float16* Xh = (_Float16*)As;
    _Float16* Wh = (_Float16*)Bs;
#pragma unroll
    for (int p = 0; p < 8; ++p) {
        int row = p * 16 + srow;
        float4 vx = *(const float4*)(xr + (size_t)(by * 128 + row) * RDIM + schunk * 4);
        *(v4h*)(Xh + row * 72 + schunk * 4) =
            (v4h){(_Float16)vx.x, (_Float16)vx.y, (_Float16)vx.z, (_Float16)vx.w};
        float4 vw = *(const float4*)(wo + (size_t)(bx * 128 + row) * RDIM + schunk * 4);
        *(v4h*)(Wh + row * 72 + schunk * 4) =
            (v4h){(_Float16)vw.x, (_Float16)vw.y, (_Float16)vw.z, (_Float16)vw.w};
    }
    __syncthreads();

    v4f facc[4][4];
#pragma unroll
    for (int i = 0; i < 4; ++i)
#pragma unroll
        for (int j = 0; j < 4; ++j) facc[i][j] = (v4f){0.f, 0.f, 0.f, 0.f};

    const int lkh = (lane >> 4) * 8;
#pragma unroll
    for (int ks = 0; ks < 2; ++ks) {
        v8h ah[4], bh[4];
#pragma unroll
        for (int i = 0; i < 4; ++i)
            ah[i] = *(const v8h*)(Xh + (wm * 64 + i * 16 + lr) * 72 + ks * 32 + lkh);
#pragma unroll
        for (int j = 0; j < 4; ++j)
            bh[j] = *(const v8h*)(Wh + (wn * 64 + j * 16 + lr) * 72 + ks * 32 + lkh);
#pragma unroll
        for (int i = 0; i < 4; ++i)
#pragma unroll
            for (int j = 0; j < 4; ++j)
                facc[i][j] = __builtin_amdgcn_mfma_f32_16x16x32_f16(ah[i], bh[j], facc[i][j], 0, 0, 0);
    }

#pragma unroll
    for (int i = 0; i < 4; ++i) {
        int row0 = wm * 64 + i * 16 + (lane >> 4) * 4;
#pragma unroll
        for (int j = 0; j < 4; ++j) {
            int col = wn * 64 + j * 16 + lr;
            float sw = ws_s[col];
            float bz = bs_s[col];
#pragma unroll
            for (int r = 0; r < 4; ++r) {
                int row = row0 + r;
                float v = (float)acc[i][j][r] * xs_s[row] * sw + bz + facc[i][j][r];
                out[(size_t)(by * 128 + row) * NDIM + (bx * 128 + col)] = v;
            }
        }
    }
}

extern "C" void kernel_launch(void* const* d_in, const int* in_sizes, int n_in,
                              void* d_out, int out_size, void* d_ws, size_t ws_size,
                              hipStream_t stream) {
    const int*   xq   = (const int*)d_in[0];
    const float* xsc  = (const float*)d_in[1];
    const int*   wq   = (const int*)d_in[2];
    const float* wsc  = (const float*)d_in[3];
    const float* bias = (const float*)d_in[4];
    const float* xr   = (const float*)d_in[5];
    const float* wo   = (const float*)d_in[6];
    float* out = (float*)d_out;

    const size_t X8 = (size_t)MDIM * KDIM;
    const size_t W8 = (size_t)NDIM * KDIM;

    if (ws_size >= X8 + W8) {
        char* x8 = (char*)d_ws;
        char* w8 = x8 + X8;
        repack_int4<<<2048, 256, 0, stream>>>(xq, wq, x8, w8);
        w4a4_g32b<<<(MDIM / 256) * (NDIM / 256), 512, 0, stream>>>(
            x8, w8, xsc, wsc, bias, xr, wo, out);
    } else {
        w4a4_fused<<<(MDIM / 128) * (NDIM / 128), 256, 0, stream>>>(
            xq, xsc, wq, wsc, bias, xr, wo, out);
    }
}

// Round 15
// 175.025 us; speedup vs baseline: 1.1220x; 1.0019x over previous
//
#include <hip/hip_runtime.h>
#include <hip/hip_fp16.h>

typedef int      v4i __attribute__((ext_vector_type(4)));
typedef int      v2i __attribute__((ext_vector_type(2)));
typedef float    v4f __attribute__((ext_vector_type(4)));
typedef _Float16 v8h __attribute__((ext_vector_type(8)));
typedef _Float16 v4h __attribute__((ext_vector_type(4)));

#define MDIM 8192
#define NDIM 4096
#define KDIM 4096
#define RDIM 64
#define KW   (KDIM / 2)
#define NT   (KDIM / 128)        // 32 K-tiles of BK=128 int8

typedef const __attribute__((address_space(1))) char* gas_ptr;
typedef __attribute__((address_space(3))) char*       las_ptr;

__device__ __forceinline__ void unpack_w(v4i w, int& lo8, int& hi8) {
    unsigned p01 = __builtin_amdgcn_perm((unsigned)w.y, (unsigned)w.x, 0x0C0C0400u);
    unsigned p23 = __builtin_amdgcn_perm((unsigned)w.w, (unsigned)w.z, 0x0C0C0400u);
    unsigned b4  = __builtin_amdgcn_perm(p23, p01, 0x05040100u);
    unsigned lo = b4 & 0x0F0F0F0Fu;
    unsigned hi = (b4 >> 4) & 0x0F0F0F0Fu;
    lo8 = (int)(((lo ^ 0x08080808u) + 0x78787878u) ^ 0x80808080u);
    hi8 = (int)(((hi ^ 0x08080808u) + 0x78787878u) ^ 0x80808080u);
}

// ---------------- kernel 1: repack packed-int32 nibbles -> dense int8 -------
__global__ __launch_bounds__(256)
void repack_int4(const int* __restrict__ xq, const int* __restrict__ wq,
                 char* __restrict__ x8, char* __restrict__ w8)
{
    const size_t XCH = (size_t)MDIM * KW / 4;
    const size_t TCH = XCH + (size_t)NDIM * KW / 4;
    size_t stride = (size_t)gridDim.x * blockDim.x;
    for (size_t i = (size_t)blockIdx.x * blockDim.x + threadIdx.x; i < TCH; i += stride) {
        const int* src;
        char* dst;
        if (i < XCH) { src = xq + i * 4; dst = x8 + i * 8; }
        else { size_t j = i - XCH; src = wq + j * 4; dst = w8 + j * 8; }
        v4i w = *(const v4i*)src;
        int lo8, hi8;
        unpack_w(w, lo8, hi8);
        *(v2i*)dst = (v2i){lo8, hi8};
    }
}

// ---------------- kernel 2: 256x256 merged-4-phase int8 GEMM ----------------
// r5 structure (best measured: GEMM 147.4us, MfmaUtil 42.8%) + T5 setprio
// around the MFMA cluster (m218b/m224: +21-39% on deep-phase structures),
// SGB weave removed (T19: null-as-graft; conflicts with setprio edges).
__device__ __forceinline__ void stage2(const char* g, char* l, int kt, int ks) {
    const char* s = g + kt * 128 + ks * 64;
    __builtin_amdgcn_global_load_lds((gas_ptr)(const void*)s,
                                     (las_ptr)(void*)l, 16, 0, 0);
    __builtin_amdgcn_global_load_lds((gas_ptr)(const void*)(s + (size_t)128 * KDIM),
                                     (las_ptr)(void*)(l + 8192), 16, 0, 0);
}

#define BAR asm volatile("s_barrier" ::: "memory")
#define VM4 asm volatile("s_waitcnt vmcnt(4)" ::: "memory")

#define READ_A8(dst, PAR, KS)                                                  \
    _Pragma("unroll")                                                          \
    for (int ii = 0; ii < 8; ++ii)                                             \
        dst[ii] = *(const v4i*)((const char*)Asub[PAR][KS] + aoff + ii * 1024)

#define READ_B4(dst, PAR, KS)                                                  \
    _Pragma("unroll")                                                          \
    for (int jj = 0; jj < 4; ++jj)                                             \
        dst[jj] = *(const v4i*)((const char*)Bsub[PAR][KS] + boff + jj * 1024)

#define MMA32(AS, BS)                                                          \
    __builtin_amdgcn_s_setprio(1);                                             \
    _Pragma("unroll")                                                          \
    for (int ii = 0; ii < 8; ++ii)                                             \
        _Pragma("unroll")                                                      \
        for (int jj = 0; jj < 4; ++jj)                                         \
            acc[ii][jj] = __builtin_amdgcn_mfma_i32_16x16x64_i8(               \
                AS[ii], BS[jj], acc[ii][jj], 0, 0, 0);                         \
    __builtin_amdgcn_s_setprio(0)

// CUR set computed; NXT set read-ahead from [NPAR][NKS]; stage [SPAR][SKS]<-SKT
#define QPHASE(CA, CB, NA, NB, NPAR, NKS, SPAR, SKS, SKT) do {                 \
    READ_A8(NA, NPAR, NKS);                                                    \
    READ_B4(NB, NPAR, NKS);                                                    \
    stage2(gA, &Asub[SPAR][SKS][ldsW], SKT, SKS);                              \
    stage2(gB, &Bsub[SPAR][SKS][ldsW], SKT, SKS);                              \
    MMA32(CA, CB);                                                             \
    VM4; BAR;                                                                  \
} while (0)

__global__ __launch_bounds__(512, 2)
void w4a4_gemm8(const char* __restrict__ x8, const char* __restrict__ w8,
                const float* __restrict__ xsc, const float* __restrict__ wsc,
                const float* __restrict__ bias, const float* __restrict__ xr,
                const float* __restrict__ wo, float* __restrict__ out)
{
    // [parity][k-half][256 rows x 64B], swizzled: byte c of row r holds
    // global col c ^ (((r>>1)&3)<<4). 128 KiB total.
    __shared__ __align__(16) char Asub[2][2][16384];
    __shared__ __align__(16) char Bsub[2][2][16384];
    __shared__ float xs_s[256];
    __shared__ float ws_s[256];
    __shared__ float bs_s[256];

    const int tid  = threadIdx.x;
    const int lane = tid & 63;
    const int wid  = tid >> 6;     // 0..7
    const int wm   = wid >> 2;     // M half (0..1)
    const int wn   = wid & 3;      // N quarter (0..3)

    // bijective XCD swizzle: 512 blocks = 8 XCDs x 64
    const int s  = (blockIdx.x & 7) * 64 + (blockIdx.x >> 3);
    const int by = s >> 4;         // 0..31
    const int bxn = s & 15;        // 0..15

    if (tid < 256) {
        xs_s[tid] = xsc[by * 256 + tid];
    } else {
        int n = tid - 256;
        ws_s[n] = wsc[bxn * 256 + n];
        bs_s[n] = bias[bxn * 256 + n];
    }

    // staging geometry: lane covers 16B of row (wid*16 + lane/4), pre-swizzled col
    const int srow = wid * 16 + (lane >> 2);
    const int scol = ((lane & 3) * 16) ^ (((lane >> 3) & 3) << 4);
    const char* gA = x8 + (size_t)(by * 256 + srow) * KDIM + scol;
    const char* gB = w8 + (size_t)(bxn * 256 + srow) * KDIM + scol;
    const int ldsW = wid * 1024;

    // fragment read geometry (swizzle XOR is lane-constant)
    const int lr   = lane & 15;
    const int cef  = ((lane >> 4) << 4) ^ (((lr >> 1) & 3) << 4);
    const int aoff = (wm * 128 + lr) * 64 + cef;
    const int boff = (wn * 64  + lr) * 64 + cef;

    v4i acc[8][4];
#pragma unroll
    for (int i = 0; i < 8; ++i)
#pragma unroll
        for (int j = 0; j < 4; ++j) acc[i][j] = (v4i){0, 0, 0, 0};

    // prologue: stage [0][0]@kt0, [0][1]@kt0, [1][0]@kt1 (12 loads/wave)
    stage2(gA, &Asub[0][0][ldsW], 0, 0);
    stage2(gB, &Bsub[0][0][ldsW], 0, 0);
    stage2(gA, &Asub[0][1][ldsW], 0, 1);
    stage2(gB, &Bsub[0][1][ldsW], 0, 1);
    stage2(gA, &Asub[1][0][ldsW], 1, 0);
    stage2(gB, &Bsub[1][0][ldsW], 1, 0);
    VM4;                                   // certify [0][0] + [0][1]
    BAR;

    // ping-pong fragment sets; read-ahead by exactly one phase
    v4i fa0[8], fb0[4], fa1[8], fb1[4];
    READ_A8(fa0, 0, 0);
    READ_B4(fb0, 0, 0);

    // Ledger (4 loads/phase/wave): stage at Qi is ds_read at Qi+2; VM4 at
    // every phase end certifies through the loads staged 2 phases earlier.
    // Q1-end drains to Q1's 4 -> certifies prologue [1][0] (read at Q2).
    // Steady state identical by induction. WAR: every stage targets a slot
    // whose last reads completed >=1 phase earlier.
    for (int it = 0; it < NT / 2; ++it) {
        const int kt1 = 2 * it + 1;
        const int kt2 = (2 * it + 2 < NT) ? 2 * it + 2 : NT - 1;
        const int kt3 = (2 * it + 3 < NT) ? 2 * it + 3 : NT - 1;
        // Q1: compute [0][0]; read [0][1]; stage [1][1]@kt1
        QPHASE(fa0, fb0, fa1, fb1, 0, 1, 1, 1, kt1);
        // Q2: compute [0][1]; read [1][0]; stage [0][0]@kt2
        QPHASE(fa1, fb1, fa0, fb0, 1, 0, 0, 0, kt2);
        // Q3: compute [1][0]; read [1][1]; stage [0][1]@kt2
        QPHASE(fa0, fb0, fa1, fb1, 1, 1, 0, 1, kt2);
        // Q4: compute [1][1]; read [0][0](next kt); stage [1][0]@kt3
        QPHASE(fa1, fb1, fa0, fb0, 0, 0, 1, 0, kt3);
    }

    // drain DMAs before overwriting LDS with the f16 outlier tiles
    asm volatile("s_waitcnt vmcnt(0)" ::: "memory");
    BAR;

    _Float16* Xh = (_Float16*)&Asub[0][0][0];   // [256][72] f16
    _Float16* Wh = (_Float16*)&Bsub[0][0][0];
    {
        const int rr = tid >> 3;
        const int c8 = (tid & 7) * 8;
#pragma unroll
        for (int p = 0; p < 4; ++p) {
            const int row = p * 64 + rr;
            v4f x0 = *(const v4f*)(xr + (size_t)(by * 256 + row) * RDIM + c8);
            v4f x1 = *(const v4f*)(xr + (size_t)(by * 256 + row) * RDIM + c8 + 4);
            v8h hx = {(_Float16)x0[0], (_Float16)x0[1], (_Float16)x0[2], (_Float16)x0[3],
                      (_Float16)x1[0], (_Float16)x1[1], (_Float16)x1[2], (_Float16)x1[3]};
            *(v8h*)((char*)Xh + (size_t)row * 144 + c8 * 2) = hx;
            v4f w0 = *(const v4f*)(wo + (size_t)(bxn * 256 + row) * RDIM + c8);
            v4f w1 = *(const v4f*)(wo + (size_t)(bxn * 256 + row) * RDIM + c8 + 4);
            v8h hw = {(_Float16)w0[0], (_Float16)w0[1], (_Float16)w0[2], (_Float16)w0[3],
                      (_Float16)w1[0], (_Float16)w1[1], (_Float16)w1[2], (_Float16)w1[3]};
            *(v8h*)((char*)Wh + (size_t)row * 144 + c8 * 2) = hw;
        }
    }

    // dequant in place (int acc -> f32 bits), overlaps the LDS staging above
#pragma unroll
    for (int i = 0; i < 8; ++i) {
        const int r0 = wm * 128 + i * 16 + ((lane >> 4) << 2);
        const v4f xs4 = *(const v4f*)&xs_s[r0];
#pragma unroll
        for (int j = 0; j < 4; ++j) {
            const int col = wn * 64 + j * 16 + lr;
            const float sw = ws_s[col];
            const float bz = bs_s[col];
            v4f f;
#pragma unroll
            for (int r = 0; r < 4; ++r)
                f[r] = (float)acc[i][j][r] * xs4[r] * sw + bz;
            acc[i][j] = __builtin_bit_cast(v4i, f);
        }
    }
    __syncthreads();

    // rank-64 outlier, f16 MFMA accumulating into the dequantized f32 frags
#pragma unroll
    for (int ks = 0; ks < 2; ++ks) {
        v8h ah[8], bh[4];
#pragma unroll
        for (int i = 0; i < 8; ++i)
            ah[i] = *(const v8h*)((const char*)Xh +
                     (size_t)(wm * 128 + i * 16 + lr) * 144 + ks * 64 + ((lane >> 4) << 4));
#pragma unroll
        for (int j = 0; j < 4; ++j)
            bh[j] = *(const v8h*)((const char*)Wh +
                     (size_t)(wn * 64 + j * 16 + lr) * 144 + ks * 64 + ((lane >> 4) << 4));
#pragma unroll
        for (int i = 0; i < 8; ++i)
#pragma unroll
            for (int j = 0; j < 4; ++j) {
                v4f c = __builtin_bit_cast(v4f, acc[i][j]);
                c = __builtin_amdgcn_mfma_f32_16x16x32_f16(ah[i], bh[j], c, 0, 0, 0);
                acc[i][j] = __builtin_bit_cast(v4i, c);
            }
    }

    const size_t obase = (size_t)(by * 256 + wm * 128 + ((lane >> 4) << 2)) * NDIM
                       + bxn * 256 + wn * 64 + lr;
#pragma unroll
    for (int i = 0; i < 8; ++i)
#pragma unroll
        for (int j = 0; j < 4; ++j) {
            v4f f = __builtin_bit_cast(v4f, acc[i][j]);
#pragma unroll
            for (int r = 0; r < 4; ++r)
                out[obase + (size_t)(i * 16 + r) * NDIM + j * 16] = f[r];
        }
}

// ---------------- fallback: fused single-kernel path (ws too small) --------
__global__ __launch_bounds__(256, 2)
void w4a4_fused(const int* __restrict__ xq, const float* __restrict__ xsc,
                const int* __restrict__ wq, const float* __restrict__ wsc,
                const float* __restrict__ bias, const float* __restrict__ xr,
                const float* __restrict__ wo, float* __restrict__ out)
{
    __shared__ __align__(16) char As[128 * 144];
    __shared__ __align__(16) char Bs[128 * 144];
    __shared__ float xs_s[128];
    __shared__ float ws_s[128];
    __shared__ float bs_s[128];

    const int tid  = threadIdx.x;
    const int lane = tid & 63;
    const int wid  = tid >> 6;
    const int wm   = wid >> 1;
    const int wn   = wid & 1;
    const int bx   = blockIdx.x % (NDIM / 128);
    const int by   = blockIdx.x / (NDIM / 128);

    const int srow   = tid >> 4;
    const int schunk = tid & 15;

    if (tid < 128) {
        xs_s[tid] = xsc[by * 128 + tid];
    } else {
        int n = tid - 128;
        ws_s[n] = wsc[bx * 128 + n];
        bs_s[n] = bias[bx * 128 + n];
    }

    const int* gA = xq + (size_t)(by * 128 + srow) * KW + schunk * 4;
    const int* gB = wq + (size_t)(bx * 128 + srow) * KW + schunk * 4;
    char* lA = As + srow * 144 + schunk * 8;
    char* lB = Bs + srow * 144 + schunk * 8;

    v4i acc[4][4];
#pragma unroll
    for (int i = 0; i < 4; ++i)
#pragma unroll
        for (int j = 0; j < 4; ++j) acc[i][j] = (v4i){0, 0, 0, 0};

    const int lr = lane & 15;
    const int lkb = (lane >> 4) * 16;

    for (int kt = 0; kt < KDIM / 128; ++kt) {
#pragma unroll
        for (int p = 0; p < 8; ++p) {
            v4i w = *(const v4i*)(gA + (size_t)p * 16 * KW + kt * 64);
            int lo8, hi8;
            unpack_w(w, lo8, hi8);
            *(v2i*)(lA + p * 16 * 144) = (v2i){lo8, hi8};
        }
#pragma unroll
        for (int p = 0; p < 8; ++p) {
            v4i w = *(const v4i*)(gB + (size_t)p * 16 * KW + kt * 64);
            int lo8, hi8;
            unpack_w(w, lo8, hi8);
            *(v2i*)(lB + p * 16 * 144) = (v2i){lo8, hi8};
        }
        __syncthreads();
#pragma unroll
        for (int ks = 0; ks < 2; ++ks) {
            v4i av[4], bv[4];
#pragma unroll
            for (int i = 0; i < 4; ++i)
                av[i] = *(const v4i*)(As + (wm * 64 + i * 16 + lr) * 144 + ks * 64 + lkb);
#pragma unroll
            for (int j = 0; j < 4; ++j)
                bv[j] = *(const v4i*)(Bs + (wn * 64 + j * 16 + lr) * 144 + ks * 64 + lkb);
#pragma unroll
            for (int i = 0; i < 4; ++i)
#pragma unroll
                for (int j = 0; j < 4; ++j)
                    acc[i][j] = __builtin_amdgcn_mfma_i32_16x16x64_i8(av[i], bv[j], acc[i][j], 0, 0, 0);
        }
        __syncthreads();
    }

    _Float16* Xh = (_Float16*)As;
    _Float16* Wh = (_Float16*)Bs;
#pragma unroll
    for (int p = 0; p < 8; ++p) {
        int row = p * 16 + srow;
        float4 vx = *(const float4*)(xr + (size_t)(by * 128 + row) * RDIM + schunk * 4);
        *(v4h*)(Xh + row * 72 + schunk * 4) =
            (v4h){(_Float16)vx.x, (_Float16)vx.y, (_Float16)vx.z, (_Float16)vx.w};
        float4 vw = *(const float4*)(wo + (size_t)(bx * 128 + row) * RDIM + schunk * 4);
        *(v4h*)(Wh + row * 72 + schunk * 4) =
            (v4h){(_Float16)vw.x, (_Float16)vw.y, (_Float16)vw.z, (_Float16)vw.w};
    }
    __syncthreads();

    v4f facc[4][4];
#pragma unroll
    for (int i = 0; i < 4; ++i)
#pragma unroll
        for (int j = 0; j < 4; ++j) facc[i][j] = (v4f){0.f, 0.f, 0.f, 0.f};

    const int lkh = (lane >> 4) * 8;
#pragma unroll
    for (int ks = 0; ks < 2; ++ks) {
        v8h ah[4], bh[4];
#pragma unroll
        for (int i = 0; i < 4; ++i)
            ah[i] = *(const v8h*)(Xh + (wm * 64 + i * 16 + lr) * 72 + ks * 32 + lkh);
#pragma unroll
        for (int j = 0; j < 4; ++j)
            bh[j] = *(const v8h*)(Wh + (wn * 64 + j * 16 + lr) * 72 + ks * 32 + lkh);
#pragma unroll
        for (int i = 0; i < 4; ++i)
#pragma unroll
            for (int j = 0; j < 4; ++j)
                facc[i][j] = __builtin_amdgcn_mfma_f32_16x16x32_f16(ah[i], bh[j], facc[i][j], 0, 0, 0);
    }

#pragma unroll
    for (int i = 0; i < 4; ++i) {
        int row0 = wm * 64 + i * 16 + (lane >> 4) * 4;
#pragma unroll
        for (int j = 0; j < 4; ++j) {
            int col = wn * 64 + j * 16 + lr;
            float sw = ws_s[col];
            float bz = bs_s[col];
#pragma unroll
            for (int r = 0; r < 4; ++r) {
                int row = row0 + r;
                float v = (float)acc[i][j][r] * xs_s[row] * sw + bz + facc[i][j][r];
                out[(size_t)(by * 128 + row) * NDIM + (bx * 128 + col)] = v;
            }
        }
    }
}

extern "C" void kernel_launch(void* const* d_in, const int* in_sizes, int n_in,
                              void* d_out, int out_size, void* d_ws, size_t ws_size,
                              hipStream_t stream) {
    const int*   xq   = (const int*)d_in[0];
    const float* xsc  = (const float*)d_in[1];
    const int*   wq   = (const int*)d_in[2];
    const float* wsc  = (const float*)d_in[3];
    const float* bias = (const float*)d_in[4];
    const float* xr   = (const float*)d_in[5];
    const float* wo   = (const float*)d_in[6];
    float* out = (float*)d_out;

    const size_t X8 = (size_t)MDIM * KDIM;
    const size_t W8 = (size_t)NDIM * KDIM;

    if (ws_size >= X8 + W8) {
        char* x8 = (char*)d_ws;
        char* w8 = x8 + X8;
        repack_int4<<<2048, 256, 0, stream>>>(xq, wq, x8, w8);
        w4a4_gemm8<<<(MDIM / 256) * (NDIM / 256), 512, 0, stream>>>(
            x8, w8, xsc, wsc, bias, xr, wo, out);
    } else {
        w4a4_fused<<<(MDIM / 128) * (NDIM / 128), 256, 0, stream>>>(
            xq, xsc, wq, wsc, bias, xr, wo, out);
    }
}